// Round 22
// baseline (925.308 us; speedup 1.0000x reference)
//
#include <hip/hip_runtime.h>
#include <math.h>

#define TT 256
#define HH 100
#define GG 400
#define BB 512

typedef float  f32x4  __attribute__((ext_vector_type(4)));
typedef short  bf16x8 __attribute__((ext_vector_type(8)));

// ---- DPP quad-perm helpers (C++ recur for layer 0) -------------------------
#define DPP_ROT1 147
#define DPP_ROT2 78
#define DPP_ROT3 57
#define DPP_XOR1 177
#define DPP_XOR2 78
#define DPP_XOR3 27

template<int CTRL>
__device__ __forceinline__ float dppf(float v) {
    int i = __float_as_int(v);
    int r = __builtin_amdgcn_update_dpp(i, i, CTRL, 0xf, 0xf, false);
    return __int_as_float(r);
}

__device__ __forceinline__ float fexp2(float x) {
    float r; asm("v_exp_f32 %0, %1" : "=v"(r) : "v"(x)); return r;
}
__device__ __forceinline__ float frcp(float x) {
    float r; asm("v_rcp_f32 %0, %1" : "=v"(r) : "v"(x)); return r;
}
#define LOG2E 1.44269504088896f

__device__ __forceinline__ unsigned bf16rne(float x) {
    unsigned b = __float_as_uint(x);
    return (b + 0x7FFFu + ((b >> 16) & 1u)) >> 16;
}

__device__ __forceinline__ void bar_lds() {
    asm volatile("s_waitcnt lgkmcnt(0)" ::: "memory");
    __builtin_amdgcn_s_barrier();
    asm volatile("" ::: "memory");
}

// ======================= layer-0 recurrence (C++, R19) =======================
template<int LK>
__global__ void __launch_bounds__(448, 2)
lstm_recur(const float* __restrict__ x, const float* __restrict__ pre,
           const float* __restrict__ Whh, const float* __restrict__ Wih0,
           const float* __restrict__ bih, const float* __restrict__ bhh,
           const float* __restrict__ head_w, const float* __restrict__ head_b,
           float* __restrict__ hs, float* __restrict__ out)
{
    __shared__ float hbuf[2][4][28];

    const int tid = threadIdx.x;
    const int b   = blockIdx.x;
    const int u   = tid >> 2, ty = tid & 3;
    const int g   = ty * HH + u;
    const bool on = (tid < GG);

    float Wq[4][25];
    float w0a = 0.f, w0b = 0.f, bias = 0.f;
    if (on) {
        #pragma unroll
        for (int d = 0; d < 4; ++d) {
            const float* wrow = Whh + (((ty + d) & 3) * HH + u) * HH + 25 * ty;
            #pragma unroll
            for (int k = 0; k < 25; ++k) Wq[d][k] = wrow[k];
        }
        if (LK == 0) {
            w0a = Wih0[2 * g]; w0b = Wih0[2 * g + 1];
            bias = bih[g] + bhh[g];
        }
    }
    if (tid < 224) (&hbuf[0][0][0])[tid] = 0.f;
    float c = 0.f;
    const int q_w = u / 25, i_w = u % 25;
    __syncthreads();

    float p0 = 0.f;
    float2 xa = {0.f, 0.f};
    if (on) {
        if (LK == 0) xa = *(const float2*)(x + (size_t)b * TT * 2);
        else         p0 = pre[((size_t)0 * BB + b) * GG + g];
    }

    for (int t = 0; t < TT; ++t) {
        const int cur = t & 1, nxt = cur ^ 1;
        if (on) {
            float ext;
            if (LK == 0) ext = bias + w0a * xa.x + w0b * xa.y;
            else         ext = p0;

            const int tn = (t + 1 < TT) ? t + 1 : t;
            if (LK == 0) xa = *(const float2*)(x + ((size_t)b * TT + tn) * 2);
            else         p0 = pre[((size_t)tn * BB + b) * GG + g];

            const float4* hq = (const float4*)&hbuf[cur][ty][0];

            float pA = 0.f, pB = 0.f, pC = 0.f, pD = 0.f;
            #pragma unroll
            for (int i = 0; i < 6; ++i) {
                const float4 h4 = hq[i];
                pA += Wq[0][4*i+0] * h4.x; pB += Wq[1][4*i+0] * h4.x;
                pC += Wq[2][4*i+0] * h4.x; pD += Wq[3][4*i+0] * h4.x;
                pA += Wq[0][4*i+1] * h4.y; pB += Wq[1][4*i+1] * h4.y;
                pC += Wq[2][4*i+1] * h4.y; pD += Wq[3][4*i+1] * h4.y;
                pA += Wq[0][4*i+2] * h4.z; pB += Wq[1][4*i+2] * h4.z;
                pC += Wq[2][4*i+2] * h4.z; pD += Wq[3][4*i+2] * h4.z;
                pA += Wq[0][4*i+3] * h4.w; pB += Wq[1][4*i+3] * h4.w;
                pC += Wq[2][4*i+3] * h4.w; pD += Wq[3][4*i+3] * h4.w;
            }
            const float hl = hq[6].x;
            pA += Wq[0][24] * hl; pB += Wq[1][24] * hl;
            pC += Wq[2][24] * hl; pD += Wq[3][24] * hl;

            float tot = pA + dppf<DPP_ROT1>(pB) + dppf<DPP_ROT2>(pC)
                           + dppf<DPP_ROT3>(pD) + ext;

            const bool isG = (ty == 2);
            float v = isG ? 2.f * tot : tot;
            float s = frcp(1.f + fexp2(-LOG2E * v));
            if (isG) s = 2.f * s - 1.f;

            float B0 = dppf<DPP_XOR1>(s), C0 = dppf<DPP_XOR2>(s), D0 = dppf<DPP_XOR3>(s);

            if (ty == 0) {
                c = B0 * c + s * C0;
                float th = 2.f * frcp(1.f + fexp2(-2.f * LOG2E * c)) - 1.f;
                float hv = D0 * th;
                hbuf[nxt][q_w][i_w] = hv;
                if (LK < 2) hs[((size_t)b * TT + t) * HH + u] = hv;
            }
        }
        bar_lds();
    }

    if (LK == 2 && tid < 64) {
        const int lane = tid;
        float p = hbuf[0][lane / 25][lane % 25] * head_w[lane];
        if (lane < 36) {
            const int k2 = 64 + lane;
            p += hbuf[0][k2 / 25][k2 % 25] * head_w[k2];
        }
        #pragma unroll
        for (int off = 32; off; off >>= 1) p += __shfl_down(p, off);
        if (lane == 0) out[b] = p + head_b[0];
    }
}

// ================= layers 1/2 recurrence (whole-loop inline asm) =============
// R22 de-risking vs R20/R21 (both NaN):
//  (1) XOR gate assignment (gate (ty^d)*100+u, R5-verified algebra) -> ALL
//      cross-lane pulls are lane^k, done with guide-verified ds_swizzle
//      BitMode encodings 0x041F/0x081F/0x0C1F (no quad-perm mode).
//  (2) s_nop 1 after every v_exp/v_rcp before its consumer (no hazard
//      recognizer inside asm).
//  (3) LDS addresses as pure integers (hbuf is this kernel's only __shared__
//      -> offset 0); no flat-pointer truncation.
// hbuf [2][4][32] floats, per-buffer 0x200 B -> XOR 0x200 toggles buffers.
// W rows live in hard-clobbered v100-v208 (AGPR-banking impossible).
#define FMROW(w0,w1,w2,w3,h) \
    "v_fmac_f32 v40, v" #w0 ", v" #h "\n\t" \
    "v_fmac_f32 v41, v" #w1 ", v" #h "\n\t" \
    "v_fmac_f32 v42, v" #w2 ", v" #h "\n\t" \
    "v_fmac_f32 v43, v" #w3 ", v" #h "\n\t"

__global__ void __launch_bounds__(448, 2)
lstm_recur_asm(const float* __restrict__ pre,   // [T*B][400] bias folded
               const float* __restrict__ Whh,   // [400][100] this layer
               const float* __restrict__ head_w,
               const float* __restrict__ head_b,
               float* __restrict__ hs,          // [B][T][100] out
               float* __restrict__ out,         // [B] (head)
               int do_head)
{
    __shared__ __align__(1024) float hbuf[2][4][32];   // [buf][quarter][25+7pad]

    const int tid = threadIdx.x;
    const int b   = blockIdx.x;
    const int u   = tid >> 2, ty = tid & 3;
    const int uc  = (u < 100) ? u : 99;
    const int g   = ty * HH + uc;
    const bool on = (tid < GG);

    const unsigned long long onm = __ballot(on);
    const unsigned long long t0m = __ballot(on && ty == 0);

    // W byte voffsets: slot d = gate (ty^d)*100+uc, k-quarter ty
    unsigned wo0 = (unsigned)((((ty ^ 0)) * 100 + uc) * 400 + ty * 100);
    unsigned wo1 = (unsigned)((((ty ^ 1)) * 100 + uc) * 400 + ty * 100);
    unsigned wo2 = (unsigned)((((ty ^ 2)) * 100 + uc) * 400 + ty * 100);
    unsigned wo3 = (unsigned)((((ty ^ 3)) * 100 + uc) * 400 + ty * 100);
    unsigned pvo    = (unsigned)((b * 400 + g) * 4);
    unsigned pvomax = pvo + 255u * 819200u;
    unsigned hso    = (unsigned)(b * 102400 + uc * 4);
    // LDS byte offsets (hbuf at LDS offset 0; buffers differ by bit 0x200)
    unsigned hrb = (unsigned)(ty * 128);
    unsigned hwb = 0x200u + (unsigned)((uc / 25) * 128 + (uc % 25) * 4);
    float mg = (ty == 2) ? -2.8853900818f : -1.4426950409f;
    float pk = (ty == 2) ? 2.f : 1.f;
    float qk = (ty == 2) ? -1.f : 0.f;

    if (tid < 256) (&hbuf[0][0][0])[tid] = 0.f;   // zero both bufs incl. pads
    __syncthreads();

    asm volatile(
        // ---- preamble ----
        "s_mov_b64 s[34:35], exec\n\t"
        "s_mov_b64 exec, %[onm]\n\t"
        "v_mov_b32 v2, %[wo0]\n\t"
        "v_mov_b32 v3, %[wo1]\n\t"
        "v_mov_b32 v4, %[wo2]\n\t"
        "v_mov_b32 v5, %[wo3]\n\t"
        "v_mov_b32 v6, %[pvo]\n\t"
        "v_mov_b32 v7, %[hso]\n\t"
        "v_mov_b32 v8, %[hrb]\n\t"
        "v_mov_b32 v9, %[hwb]\n\t"
        "v_mov_b32 v60, 0\n\t"
        // W slot 0 -> v100+k
        "global_load_dwordx4 v[100:103], v2, %[whh]\n\t"
        "global_load_dwordx4 v[104:107], v2, %[whh] offset:16\n\t"
        "global_load_dwordx4 v[108:111], v2, %[whh] offset:32\n\t"
        "global_load_dwordx4 v[112:115], v2, %[whh] offset:48\n\t"
        "global_load_dwordx4 v[116:119], v2, %[whh] offset:64\n\t"
        "global_load_dwordx4 v[120:123], v2, %[whh] offset:80\n\t"
        "global_load_dword v124, v2, %[whh] offset:96\n\t"
        // W slot 1 -> v128+k
        "global_load_dwordx4 v[128:131], v3, %[whh]\n\t"
        "global_load_dwordx4 v[132:135], v3, %[whh] offset:16\n\t"
        "global_load_dwordx4 v[136:139], v3, %[whh] offset:32\n\t"
        "global_load_dwordx4 v[140:143], v3, %[whh] offset:48\n\t"
        "global_load_dwordx4 v[144:147], v3, %[whh] offset:64\n\t"
        "global_load_dwordx4 v[148:151], v3, %[whh] offset:80\n\t"
        "global_load_dword v152, v3, %[whh] offset:96\n\t"
        // W slot 2 -> v156+k
        "global_load_dwordx4 v[156:159], v4, %[whh]\n\t"
        "global_load_dwordx4 v[160:163], v4, %[whh] offset:16\n\t"
        "global_load_dwordx4 v[164:167], v4, %[whh] offset:32\n\t"
        "global_load_dwordx4 v[168:171], v4, %[whh] offset:48\n\t"
        "global_load_dwordx4 v[172:175], v4, %[whh] offset:64\n\t"
        "global_load_dwordx4 v[176:179], v4, %[whh] offset:80\n\t"
        "global_load_dword v180, v4, %[whh] offset:96\n\t"
        // W slot 3 -> v184+k
        "global_load_dwordx4 v[184:187], v5, %[whh]\n\t"
        "global_load_dwordx4 v[188:191], v5, %[whh] offset:16\n\t"
        "global_load_dwordx4 v[192:195], v5, %[whh] offset:32\n\t"
        "global_load_dwordx4 v[196:199], v5, %[whh] offset:48\n\t"
        "global_load_dwordx4 v[200:203], v5, %[whh] offset:64\n\t"
        "global_load_dwordx4 v[204:207], v5, %[whh] offset:80\n\t"
        "global_load_dword v208, v5, %[whh] offset:96\n\t"
        "global_load_dword v10, v6, %[pre]\n\t"     // p(t=0)
        "s_movk_i32 s30, 0x100\n\t"
        "s_waitcnt vmcnt(0)\n\t"
        // ---- time loop ----
        "LT%=:\n\t"
        "s_waitcnt vmcnt(0)\n\t"
        "v_mov_b32 v11, v10\n\t"                    // ext = p(t)
        "v_add_u32 v6, 0xC8000, v6\n\t"             // +819200 B (next t)
        "v_min_u32 v6, v6, %[pvm]\n\t"              // clamp t<=255
        "global_load_dword v10, v6, %[pre]\n\t"     // prefetch p(t+1)
        "ds_read_b128 v[12:15], v8\n\t"
        "ds_read_b128 v[16:19], v8 offset:16\n\t"
        "ds_read_b128 v[20:23], v8 offset:32\n\t"
        "ds_read_b128 v[24:27], v8 offset:48\n\t"
        "ds_read_b128 v[28:31], v8 offset:64\n\t"
        "ds_read_b128 v[32:35], v8 offset:80\n\t"
        "ds_read_b128 v[36:39], v8 offset:96\n\t"
        "v_mov_b32 v40, 0\n\t"
        "v_mov_b32 v41, 0\n\t"
        "v_mov_b32 v42, 0\n\t"
        "v_mov_b32 v43, 0\n\t"
        "s_waitcnt lgkmcnt(0)\n\t"
        FMROW(100,128,156,184,12) FMROW(101,129,157,185,13)
        FMROW(102,130,158,186,14) FMROW(103,131,159,187,15)
        FMROW(104,132,160,188,16) FMROW(105,133,161,189,17)
        FMROW(106,134,162,190,18) FMROW(107,135,163,191,19)
        FMROW(108,136,164,192,20) FMROW(109,137,165,193,21)
        FMROW(110,138,166,194,22) FMROW(111,139,167,195,23)
        FMROW(112,140,168,196,24) FMROW(113,141,169,197,25)
        FMROW(114,142,170,198,26) FMROW(115,143,171,199,27)
        FMROW(116,144,172,200,28) FMROW(117,145,173,201,29)
        FMROW(118,146,174,202,30) FMROW(119,147,175,203,31)
        FMROW(120,148,176,204,32) FMROW(121,149,177,205,33)
        FMROW(122,150,178,206,34) FMROW(123,151,179,207,35)
        FMROW(124,152,180,208,36)
        // combine: tot_j = pA + xor1(pB) + xor2(pC) + xor3(pD) + ext
        // (BitMode: lane' = ((lane&0x1F)|0)^k — guide-verified encodings)
        "ds_swizzle_b32 v44, v41 offset:0x041F\n\t"
        "ds_swizzle_b32 v45, v42 offset:0x081F\n\t"
        "ds_swizzle_b32 v46, v43 offset:0x0C1F\n\t"
        "s_waitcnt lgkmcnt(0)\n\t"
        "v_add_f32 v40, v40, v44\n\t"
        "v_add_f32 v40, v40, v45\n\t"
        "v_add_f32 v40, v40, v46\n\t"
        "v_add_f32 v40, v40, v11\n\t"
        // activation: s = pk*rcp(1+exp2(mg*tot)) + qk
        "v_mul_f32 v47, %[mg], v40\n\t"
        "v_exp_f32 v47, v47\n\t"
        "s_nop 1\n\t"
        "v_add_f32 v47, 1.0, v47\n\t"
        "v_rcp_f32 v47, v47\n\t"
        "s_nop 1\n\t"
        "v_fma_f32 v44, %[pk], v47, %[qk]\n\t"
        // gather i/f/g/o (xor pulls)
        "ds_swizzle_b32 v45, v44 offset:0x041F\n\t"
        "ds_swizzle_b32 v46, v44 offset:0x081F\n\t"
        "ds_swizzle_b32 v48, v44 offset:0x0C1F\n\t"
        "s_waitcnt lgkmcnt(0)\n\t"
        // ty==0 lanes: c/h update (v45=sig(f), v46=tanh(g), v48=sig(o))
        "s_mov_b64 exec, %[t0m]\n\t"
        "v_mul_f32 v60, v45, v60\n\t"               // c *= sig(f)
        "v_fmac_f32 v60, v44, v46\n\t"              // c += sig(i)*tanh(g)
        "v_mul_f32 v49, 0xC038AA3B, v60\n\t"        // -2*log2e*c
        "v_exp_f32 v49, v49\n\t"
        "s_nop 1\n\t"
        "v_add_f32 v49, 1.0, v49\n\t"
        "v_rcp_f32 v49, v49\n\t"
        "s_nop 1\n\t"
        "v_fma_f32 v49, 2.0, v49, -1.0\n\t"         // tanh(c)
        "v_mul_f32 v50, v48, v49\n\t"               // h = sig(o)*tanh(c)
        "ds_write_b32 v9, v50\n\t"
        "global_store_dword v7, v50, %[hs]\n\t"
        "v_add_u32 v7, 0x190, v7\n\t"
        "s_mov_b64 exec, %[onm]\n\t"
        "v_xor_b32 v8, 0x200, v8\n\t"               // toggle read buf (bit 9)
        "v_xor_b32 v9, 0x200, v9\n\t"               // toggle write buf (bit 9)
        "s_waitcnt lgkmcnt(0)\n\t"
        "s_barrier\n\t"
        "s_sub_u32 s30, s30, 1\n\t"
        "s_cmp_lg_u32 s30, 0\n\t"
        "s_cbranch_scc1 LT%=\n\t"
        "s_mov_b64 exec, s[34:35]\n\t"
        :
        : [onm] "s"(onm), [t0m] "s"(t0m),
          [whh] "s"(Whh), [pre] "s"(pre), [hs] "s"(hs),
          [wo0] "v"(wo0), [wo1] "v"(wo1), [wo2] "v"(wo2), [wo3] "v"(wo3),
          [pvo] "v"(pvo), [pvm] "v"(pvomax), [hso] "v"(hso),
          [hrb] "v"(hrb), [hwb] "v"(hwb),
          [mg] "v"(mg), [pk] "v"(pk), [qk] "v"(qk)
        : "memory", "scc", "s30", "s34", "s35",
          "v2","v3","v4","v5","v6","v7","v8","v9","v10","v11",
          "v12","v13","v14","v15","v16","v17","v18","v19","v20","v21",
          "v22","v23","v24","v25","v26","v27","v28","v29","v30","v31",
          "v32","v33","v34","v35","v36","v37","v38","v39","v40","v41",
          "v42","v43","v44","v45","v46","v47","v48","v49","v50","v60",
          "v100","v101","v102","v103","v104","v105","v106","v107","v108","v109",
          "v110","v111","v112","v113","v114","v115","v116","v117","v118","v119",
          "v120","v121","v122","v123","v124","v125","v126","v127","v128","v129",
          "v130","v131","v132","v133","v134","v135","v136","v137","v138","v139",
          "v140","v141","v142","v143","v144","v145","v146","v147","v148","v149",
          "v150","v151","v152","v153","v154","v155","v156","v157","v158","v159",
          "v160","v161","v162","v163","v164","v165","v166","v167","v168","v169",
          "v170","v171","v172","v173","v174","v175","v176","v177","v178","v179",
          "v180","v181","v182","v183","v184","v185","v186","v187","v188","v189",
          "v190","v191","v192","v193","v194","v195","v196","v197","v198","v199",
          "v200","v201","v202","v203","v204","v205","v206","v207","v208");

    __syncthreads();
    if (do_head && tid < 64) {
        const int lane = tid;
        float p = hbuf[0][lane / 25][lane % 25] * head_w[lane];
        if (lane < 36) {
            const int k2 = 64 + lane;
            p += hbuf[0][k2 / 25][k2 % 25] * head_w[k2];
        }
        #pragma unroll
        for (int off = 32; off; off >>= 1) p += __shfl_down(p, off);
        if (lane == 0) out[b] = p + head_b[0];
    }
}

// ====================== x-projection GEMM (MFMA, persistent) =================
__global__ void __launch_bounds__(512, 1)
gemm_pre(const float* __restrict__ hs, const float* __restrict__ Wih,
         const float* __restrict__ bih, const float* __restrict__ bhh,
         float* __restrict__ pre)
{
    extern __shared__ short Ws[];

    const int tid = threadIdx.x;
    const int l   = tid & 63, w = tid >> 6;
    const int lr  = l & 15, lg = l >> 4;
    const int gbase = blockIdx.y * 200;

    {
        int* wz = (int*)Ws;
        for (int i = tid; i < 26624; i += 512) wz[i] = 0;
    }
    __syncthreads();

    for (int L = tid; L < 20000; L += 512) {
        const int g = L / 100, k = L % 100;
        const float v = Wih[(size_t)(gbase + g) * HH + k];
        const unsigned hh = bf16rne(v);
        const float rem = v - __uint_as_float(hh << 16);
        const unsigned lo = bf16rne(rem);
        const int kp = (((k >> 3) ^ (g & 15)) << 3) | (k & 7);
        Ws[(size_t)g * 128 + kp]          = (short)hh;
        Ws[(size_t)(208 + g) * 128 + kp]  = (short)lo;
    }
    __syncthreads();

    for (int c = 0; c < 8; ++c) {
        const int row0   = blockIdx.x * 1024 + c * 128;
        const int t      = row0 >> 9;
        const int b_base = row0 & 511;

        bf16x8 Ahi[4], Alo[4];
        {
            const float* hrow = hs + ((size_t)(b_base + 16 * w + lr) * TT + t) * HH;
            #pragma unroll
            for (int kt = 0; kt < 4; ++kt) {
                const int k0 = 32 * kt + 8 * lg;
                float4 v0 = {0.f,0.f,0.f,0.f}, v1 = {0.f,0.f,0.f,0.f};
                if (k0     <= 96) v0 = *(const float4*)(hrow + k0);
                if (k0 + 4 <= 96) v1 = *(const float4*)(hrow + k0 + 4);
                const float e[8] = {v0.x,v0.y,v0.z,v0.w,v1.x,v1.y,v1.z,v1.w};
                short sh[8], sl[8];
                #pragma unroll
                for (int i = 0; i < 8; ++i) {
                    const unsigned hh = bf16rne(e[i]);
                    const float rem = e[i] - __uint_as_float(hh << 16);
                    sh[i] = (short)hh;
                    sl[i] = (short)bf16rne(rem);
                }
                Ahi[kt] = (bf16x8){sh[0],sh[1],sh[2],sh[3],sh[4],sh[5],sh[6],sh[7]};
                Alo[kt] = (bf16x8){sl[0],sl[1],sl[2],sl[3],sl[4],sl[5],sl[6],sl[7]};
            }
        }

        #pragma unroll
        for (int n = 0; n < 13; ++n) {
            const int gp = 16 * n + lr;
            bf16x8 Bhi[4], Blo[4];
            #pragma unroll
            for (int kt = 0; kt < 4; ++kt) {
                const int slot = (4 * kt + lg) ^ (gp & 15);
                Bhi[kt] = *(const bf16x8*)&Ws[(size_t)gp * 128 + slot * 8];
                Blo[kt] = *(const bf16x8*)&Ws[(size_t)(208 + gp) * 128 + slot * 8];
            }
            f32x4 acc = {0.f, 0.f, 0.f, 0.f};
            #pragma unroll
            for (int kt = 0; kt < 4; ++kt) {
                acc = __builtin_amdgcn_mfma_f32_16x16x32_bf16(Ahi[kt], Bhi[kt], acc, 0, 0, 0);
                acc = __builtin_amdgcn_mfma_f32_16x16x32_bf16(Alo[kt], Bhi[kt], acc, 0, 0, 0);
                acc = __builtin_amdgcn_mfma_f32_16x16x32_bf16(Ahi[kt], Blo[kt], acc, 0, 0, 0);
            }
            if (gp < 200) {
                const int gcol = gbase + gp;
                const float bsum = bih[gcol] + bhh[gcol];
                #pragma unroll
                for (int r = 0; r < 4; ++r) {
                    const size_t row = (size_t)row0 + 16 * w + 4 * lg + r;
                    pre[row * GG + gcol] = acc[r] + bsum;
                }
            }
        }
    }
}

// =============================================================================
extern "C" void kernel_launch(void* const* d_in, const int* in_sizes, int n_in,
                              void* d_out, int out_size, void* d_ws, size_t ws_size,
                              hipStream_t stream) {
    const float* x         = (const float*)d_in[0];
    const float* W_ih0     = (const float*)d_in[1];
    const float* W_ih_rest = (const float*)d_in[2];
    const float* W_hh      = (const float*)d_in[3];
    const float* b_ih      = (const float*)d_in[4];
    const float* b_hh      = (const float*)d_in[5];
    const float* head_w    = (const float*)d_in[6];
    const float* head_b    = (const float*)d_in[7];
    float* out = (float*)d_out;

    const size_t HS_BYTES = (size_t)BB * TT * HH * 4;
    float* hs  = (float*)d_ws;
    float* pre = (float*)((char*)d_ws + HS_BYTES);

    const int gemm_lds = 2 * 208 * 128 * 2;
    hipFuncSetAttribute((const void*)gemm_pre,
                        hipFuncAttributeMaxDynamicSharedMemorySize, gemm_lds);
    dim3 ggrid(128, 2);

    lstm_recur<0><<<512, 448, 0, stream>>>(
        x, nullptr, W_hh, W_ih0, b_ih, b_hh, head_w, head_b, hs, out);

    gemm_pre<<<ggrid, 512, gemm_lds, stream>>>(hs, W_ih_rest, b_ih + GG, b_hh + GG, pre);
    lstm_recur_asm<<<512, 448, 0, stream>>>(
        pre, W_hh + 40000, head_w, head_b, hs, out, 0);

    gemm_pre<<<ggrid, 512, gemm_lds, stream>>>(hs, W_ih_rest + 40000, b_ih + 2*GG, b_hh + 2*GG, pre);
    lstm_recur_asm<<<512, 448, 0, stream>>>(
        pre, W_hh + 80000, head_w, head_b, hs, out, 1);
}

// Round 23
// 859.056 us; speedup vs baseline: 1.0771x; 1.0771x over previous
//
#include <hip/hip_runtime.h>
#include <math.h>

#define TT 256
#define HH 100
#define GG 400
#define BB 512

typedef float  f32x4  __attribute__((ext_vector_type(4)));
typedef short  bf16x8 __attribute__((ext_vector_type(8)));

// ---- DPP quad-perm helpers (C++ recur for layer 0) -------------------------
#define DPP_ROT1 147
#define DPP_ROT2 78
#define DPP_ROT3 57
#define DPP_XOR1 177
#define DPP_XOR2 78
#define DPP_XOR3 27

template<int CTRL>
__device__ __forceinline__ float dppf(float v) {
    int i = __float_as_int(v);
    int r = __builtin_amdgcn_update_dpp(i, i, CTRL, 0xf, 0xf, false);
    return __int_as_float(r);
}

__device__ __forceinline__ float fexp2(float x) {
    float r; asm("v_exp_f32 %0, %1" : "=v"(r) : "v"(x)); return r;
}
__device__ __forceinline__ float frcp(float x) {
    float r; asm("v_rcp_f32 %0, %1" : "=v"(r) : "v"(x)); return r;
}
#define LOG2E 1.44269504088896f

__device__ __forceinline__ unsigned bf16rne(float x) {
    unsigned b = __float_as_uint(x);
    return (b + 0x7FFFu + ((b >> 16) & 1u)) >> 16;
}

__device__ __forceinline__ void bar_lds() {
    asm volatile("s_waitcnt lgkmcnt(0)" ::: "memory");
    __builtin_amdgcn_s_barrier();
    asm volatile("" ::: "memory");
}

// ======================= layer-0 recurrence (C++, R19) =======================
template<int LK>
__global__ void __launch_bounds__(448, 2)
lstm_recur(const float* __restrict__ x, const float* __restrict__ pre,
           const float* __restrict__ Whh, const float* __restrict__ Wih0,
           const float* __restrict__ bih, const float* __restrict__ bhh,
           const float* __restrict__ head_w, const float* __restrict__ head_b,
           float* __restrict__ hs, float* __restrict__ out)
{
    __shared__ float hbuf[2][4][28];

    const int tid = threadIdx.x;
    const int b   = blockIdx.x;
    const int u   = tid >> 2, ty = tid & 3;
    const int g   = ty * HH + u;
    const bool on = (tid < GG);

    float Wq[4][25];
    float w0a = 0.f, w0b = 0.f, bias = 0.f;
    if (on) {
        #pragma unroll
        for (int d = 0; d < 4; ++d) {
            const float* wrow = Whh + (((ty + d) & 3) * HH + u) * HH + 25 * ty;
            #pragma unroll
            for (int k = 0; k < 25; ++k) Wq[d][k] = wrow[k];
        }
        if (LK == 0) {
            w0a = Wih0[2 * g]; w0b = Wih0[2 * g + 1];
            bias = bih[g] + bhh[g];
        }
    }
    if (tid < 224) (&hbuf[0][0][0])[tid] = 0.f;
    float c = 0.f;
    const int q_w = u / 25, i_w = u % 25;
    __syncthreads();

    float p0 = 0.f;
    float2 xa = {0.f, 0.f};
    if (on) {
        if (LK == 0) xa = *(const float2*)(x + (size_t)b * TT * 2);
        else         p0 = pre[((size_t)0 * BB + b) * GG + g];
    }

    for (int t = 0; t < TT; ++t) {
        const int cur = t & 1, nxt = cur ^ 1;
        if (on) {
            float ext;
            if (LK == 0) ext = bias + w0a * xa.x + w0b * xa.y;
            else         ext = p0;

            const int tn = (t + 1 < TT) ? t + 1 : t;
            if (LK == 0) xa = *(const float2*)(x + ((size_t)b * TT + tn) * 2);
            else         p0 = pre[((size_t)tn * BB + b) * GG + g];

            const float4* hq = (const float4*)&hbuf[cur][ty][0];

            float pA = 0.f, pB = 0.f, pC = 0.f, pD = 0.f;
            #pragma unroll
            for (int i = 0; i < 6; ++i) {
                const float4 h4 = hq[i];
                pA += Wq[0][4*i+0] * h4.x; pB += Wq[1][4*i+0] * h4.x;
                pC += Wq[2][4*i+0] * h4.x; pD += Wq[3][4*i+0] * h4.x;
                pA += Wq[0][4*i+1] * h4.y; pB += Wq[1][4*i+1] * h4.y;
                pC += Wq[2][4*i+1] * h4.y; pD += Wq[3][4*i+1] * h4.y;
                pA += Wq[0][4*i+2] * h4.z; pB += Wq[1][4*i+2] * h4.z;
                pC += Wq[2][4*i+2] * h4.z; pD += Wq[3][4*i+2] * h4.z;
                pA += Wq[0][4*i+3] * h4.w; pB += Wq[1][4*i+3] * h4.w;
                pC += Wq[2][4*i+3] * h4.w; pD += Wq[3][4*i+3] * h4.w;
            }
            const float hl = hq[6].x;
            pA += Wq[0][24] * hl; pB += Wq[1][24] * hl;
            pC += Wq[2][24] * hl; pD += Wq[3][24] * hl;

            float tot = pA + dppf<DPP_ROT1>(pB) + dppf<DPP_ROT2>(pC)
                           + dppf<DPP_ROT3>(pD) + ext;

            const bool isG = (ty == 2);
            float v = isG ? 2.f * tot : tot;
            float s = frcp(1.f + fexp2(-LOG2E * v));
            if (isG) s = 2.f * s - 1.f;

            float B0 = dppf<DPP_XOR1>(s), C0 = dppf<DPP_XOR2>(s), D0 = dppf<DPP_XOR3>(s);

            if (ty == 0) {
                c = B0 * c + s * C0;
                float th = 2.f * frcp(1.f + fexp2(-2.f * LOG2E * c)) - 1.f;
                float hv = D0 * th;
                hbuf[nxt][q_w][i_w] = hv;
                if (LK < 2) hs[((size_t)b * TT + t) * HH + u] = hv;
            }
        }
        bar_lds();
    }

    if (LK == 2 && tid < 64) {
        const int lane = tid;
        float p = hbuf[0][lane / 25][lane % 25] * head_w[lane];
        if (lane < 36) {
            const int k2 = 64 + lane;
            p += hbuf[0][k2 / 25][k2 % 25] * head_w[k2];
        }
        #pragma unroll
        for (int off = 32; off; off >>= 1) p += __shfl_down(p, off);
        if (lane == 0) out[b] = p + head_b[0];
    }
}

// ================= layers 1/2 recurrence (whole-loop inline asm) =============
// R22 passed (absmax 0.0) but had SQ_LDS_BANK_CONFLICT=2.39e7: the [4][32]
// layout's 128-B quarter stride put ALL ty-groups on banks 0-3 (128/4 % 32
// == 0) -> 16-way conflict on every ds_read_b128. R23 layout: quarter stride
// 144 B (16-aligned; banks q*36 mod 32 = {0,4,8,12} -> disjoint groups,
// broadcast within each), buffer stride 0x400 (max intra-buffer offset 540
// < 1024 -> XOR 0x400 is a clean buffer-select bit). hbuf = 2 KB, align 2048.
#define FMROW(w0,w1,w2,w3,h) \
    "v_fmac_f32 v40, v" #w0 ", v" #h "\n\t" \
    "v_fmac_f32 v41, v" #w1 ", v" #h "\n\t" \
    "v_fmac_f32 v42, v" #w2 ", v" #h "\n\t" \
    "v_fmac_f32 v43, v" #w3 ", v" #h "\n\t"

__global__ void __launch_bounds__(448, 2)
lstm_recur_asm(const float* __restrict__ pre,   // [T*B][400] bias folded
               const float* __restrict__ Whh,   // [400][100] this layer
               const float* __restrict__ head_w,
               const float* __restrict__ head_b,
               float* __restrict__ hs,          // [B][T][100] out
               float* __restrict__ out,         // [B] (head)
               int do_head)
{
    __shared__ __align__(2048) float hbuf[2][256];  // buf stride 0x400 B;
                                                    // quarter q at q*36 floats

    const int tid = threadIdx.x;
    const int b   = blockIdx.x;
    const int u   = tid >> 2, ty = tid & 3;
    const int uc  = (u < 100) ? u : 99;
    const int g   = ty * HH + uc;
    const bool on = (tid < GG);

    const unsigned long long onm = __ballot(on);
    const unsigned long long t0m = __ballot(on && ty == 0);

    // W byte voffsets: slot d = gate (ty^d)*100+uc, k-quarter ty
    unsigned wo0 = (unsigned)((((ty ^ 0)) * 100 + uc) * 400 + ty * 100);
    unsigned wo1 = (unsigned)((((ty ^ 1)) * 100 + uc) * 400 + ty * 100);
    unsigned wo2 = (unsigned)((((ty ^ 2)) * 100 + uc) * 400 + ty * 100);
    unsigned wo3 = (unsigned)((((ty ^ 3)) * 100 + uc) * 400 + ty * 100);
    unsigned pvo    = (unsigned)((b * 400 + g) * 4);
    unsigned pvomax = pvo + 255u * 819200u;
    unsigned hso    = (unsigned)(b * 102400 + uc * 4);
    // LDS byte offsets (hbuf is the only __shared__ -> offset 0)
    unsigned hrb = (unsigned)(ty * 144);                              // read buf0
    unsigned hwb = 0x400u + (unsigned)((uc / 25) * 144 + (uc % 25) * 4); // write buf1
    float mg = (ty == 2) ? -2.8853900818f : -1.4426950409f;
    float pk = (ty == 2) ? 2.f : 1.f;
    float qk = (ty == 2) ? -1.f : 0.f;

    // zero both buffers (512 floats)
    if (tid < 448) (&hbuf[0][0])[tid] = 0.f;
    if (tid < 64)  (&hbuf[0][0])[448 + tid] = 0.f;
    __syncthreads();

    asm volatile(
        // ---- preamble ----
        "s_mov_b64 s[34:35], exec\n\t"
        "s_mov_b64 exec, %[onm]\n\t"
        "v_mov_b32 v2, %[wo0]\n\t"
        "v_mov_b32 v3, %[wo1]\n\t"
        "v_mov_b32 v4, %[wo2]\n\t"
        "v_mov_b32 v5, %[wo3]\n\t"
        "v_mov_b32 v6, %[pvo]\n\t"
        "v_mov_b32 v7, %[hso]\n\t"
        "v_mov_b32 v8, %[hrb]\n\t"
        "v_mov_b32 v9, %[hwb]\n\t"
        "v_mov_b32 v60, 0\n\t"
        // W slot 0 -> v100+k
        "global_load_dwordx4 v[100:103], v2, %[whh]\n\t"
        "global_load_dwordx4 v[104:107], v2, %[whh] offset:16\n\t"
        "global_load_dwordx4 v[108:111], v2, %[whh] offset:32\n\t"
        "global_load_dwordx4 v[112:115], v2, %[whh] offset:48\n\t"
        "global_load_dwordx4 v[116:119], v2, %[whh] offset:64\n\t"
        "global_load_dwordx4 v[120:123], v2, %[whh] offset:80\n\t"
        "global_load_dword v124, v2, %[whh] offset:96\n\t"
        // W slot 1 -> v128+k
        "global_load_dwordx4 v[128:131], v3, %[whh]\n\t"
        "global_load_dwordx4 v[132:135], v3, %[whh] offset:16\n\t"
        "global_load_dwordx4 v[136:139], v3, %[whh] offset:32\n\t"
        "global_load_dwordx4 v[140:143], v3, %[whh] offset:48\n\t"
        "global_load_dwordx4 v[144:147], v3, %[whh] offset:64\n\t"
        "global_load_dwordx4 v[148:151], v3, %[whh] offset:80\n\t"
        "global_load_dword v152, v3, %[whh] offset:96\n\t"
        // W slot 2 -> v156+k
        "global_load_dwordx4 v[156:159], v4, %[whh]\n\t"
        "global_load_dwordx4 v[160:163], v4, %[whh] offset:16\n\t"
        "global_load_dwordx4 v[164:167], v4, %[whh] offset:32\n\t"
        "global_load_dwordx4 v[168:171], v4, %[whh] offset:48\n\t"
        "global_load_dwordx4 v[172:175], v4, %[whh] offset:64\n\t"
        "global_load_dwordx4 v[176:179], v4, %[whh] offset:80\n\t"
        "global_load_dword v180, v4, %[whh] offset:96\n\t"
        // W slot 3 -> v184+k
        "global_load_dwordx4 v[184:187], v5, %[whh]\n\t"
        "global_load_dwordx4 v[188:191], v5, %[whh] offset:16\n\t"
        "global_load_dwordx4 v[192:195], v5, %[whh] offset:32\n\t"
        "global_load_dwordx4 v[196:199], v5, %[whh] offset:48\n\t"
        "global_load_dwordx4 v[200:203], v5, %[whh] offset:64\n\t"
        "global_load_dwordx4 v[204:207], v5, %[whh] offset:80\n\t"
        "global_load_dword v208, v5, %[whh] offset:96\n\t"
        "global_load_dword v10, v6, %[pre]\n\t"     // p(t=0)
        "s_movk_i32 s30, 0x100\n\t"
        "s_waitcnt vmcnt(0)\n\t"
        // ---- time loop ----
        "LT%=:\n\t"
        "s_waitcnt vmcnt(0)\n\t"
        "v_mov_b32 v11, v10\n\t"                    // ext = p(t)
        "v_add_u32 v6, 0xC8000, v6\n\t"             // +819200 B (next t)
        "v_min_u32 v6, v6, %[pvm]\n\t"              // clamp t<=255
        "global_load_dword v10, v6, %[pre]\n\t"     // prefetch p(t+1)
        "ds_read_b128 v[12:15], v8\n\t"
        "ds_read_b128 v[16:19], v8 offset:16\n\t"
        "ds_read_b128 v[20:23], v8 offset:32\n\t"
        "ds_read_b128 v[24:27], v8 offset:48\n\t"
        "ds_read_b128 v[28:31], v8 offset:64\n\t"
        "ds_read_b128 v[32:35], v8 offset:80\n\t"
        "ds_read_b128 v[36:39], v8 offset:96\n\t"
        "v_mov_b32 v40, 0\n\t"
        "v_mov_b32 v41, 0\n\t"
        "v_mov_b32 v42, 0\n\t"
        "v_mov_b32 v43, 0\n\t"
        "s_waitcnt lgkmcnt(0)\n\t"
        FMROW(100,128,156,184,12) FMROW(101,129,157,185,13)
        FMROW(102,130,158,186,14) FMROW(103,131,159,187,15)
        FMROW(104,132,160,188,16) FMROW(105,133,161,189,17)
        FMROW(106,134,162,190,18) FMROW(107,135,163,191,19)
        FMROW(108,136,164,192,20) FMROW(109,137,165,193,21)
        FMROW(110,138,166,194,22) FMROW(111,139,167,195,23)
        FMROW(112,140,168,196,24) FMROW(113,141,169,197,25)
        FMROW(114,142,170,198,26) FMROW(115,143,171,199,27)
        FMROW(116,144,172,200,28) FMROW(117,145,173,201,29)
        FMROW(118,146,174,202,30) FMROW(119,147,175,203,31)
        FMROW(120,148,176,204,32) FMROW(121,149,177,205,33)
        FMROW(122,150,178,206,34) FMROW(123,151,179,207,35)
        FMROW(124,152,180,208,36)
        // combine: tot_j = pA + xor1(pB) + xor2(pC) + xor3(pD) + ext
        "ds_swizzle_b32 v44, v41 offset:0x041F\n\t"
        "ds_swizzle_b32 v45, v42 offset:0x081F\n\t"
        "ds_swizzle_b32 v46, v43 offset:0x0C1F\n\t"
        "s_waitcnt lgkmcnt(0)\n\t"
        "v_add_f32 v40, v40, v44\n\t"
        "v_add_f32 v40, v40, v45\n\t"
        "v_add_f32 v40, v40, v46\n\t"
        "v_add_f32 v40, v40, v11\n\t"
        // activation: s = pk*rcp(1+exp2(mg*tot)) + qk
        "v_mul_f32 v47, %[mg], v40\n\t"
        "v_exp_f32 v47, v47\n\t"
        "s_nop 1\n\t"
        "v_add_f32 v47, 1.0, v47\n\t"
        "v_rcp_f32 v47, v47\n\t"
        "s_nop 1\n\t"
        "v_fma_f32 v44, %[pk], v47, %[qk]\n\t"
        // gather i/f/g/o (xor pulls)
        "ds_swizzle_b32 v45, v44 offset:0x041F\n\t"
        "ds_swizzle_b32 v46, v44 offset:0x081F\n\t"
        "ds_swizzle_b32 v48, v44 offset:0x0C1F\n\t"
        "s_waitcnt lgkmcnt(0)\n\t"
        // ty==0 lanes: c/h update (v45=sig(f), v46=tanh(g), v48=sig(o))
        "s_mov_b64 exec, %[t0m]\n\t"
        "v_mul_f32 v60, v45, v60\n\t"               // c *= sig(f)
        "v_fmac_f32 v60, v44, v46\n\t"              // c += sig(i)*tanh(g)
        "v_mul_f32 v49, 0xC038AA3B, v60\n\t"        // -2*log2e*c
        "v_exp_f32 v49, v49\n\t"
        "s_nop 1\n\t"
        "v_add_f32 v49, 1.0, v49\n\t"
        "v_rcp_f32 v49, v49\n\t"
        "s_nop 1\n\t"
        "v_fma_f32 v49, 2.0, v49, -1.0\n\t"         // tanh(c)
        "v_mul_f32 v50, v48, v49\n\t"               // h = sig(o)*tanh(c)
        "ds_write_b32 v9, v50\n\t"
        "global_store_dword v7, v50, %[hs]\n\t"
        "v_add_u32 v7, 0x190, v7\n\t"
        "s_mov_b64 exec, %[onm]\n\t"
        "v_xor_b32 v8, 0x400, v8\n\t"               // toggle read buf (bit 10)
        "v_xor_b32 v9, 0x400, v9\n\t"               // toggle write buf (bit 10)
        "s_waitcnt lgkmcnt(0)\n\t"
        "s_barrier\n\t"
        "s_sub_u32 s30, s30, 1\n\t"
        "s_cmp_lg_u32 s30, 0\n\t"
        "s_cbranch_scc1 LT%=\n\t"
        "s_mov_b64 exec, s[34:35]\n\t"
        :
        : [onm] "s"(onm), [t0m] "s"(t0m),
          [whh] "s"(Whh), [pre] "s"(pre), [hs] "s"(hs),
          [wo0] "v"(wo0), [wo1] "v"(wo1), [wo2] "v"(wo2), [wo3] "v"(wo3),
          [pvo] "v"(pvo), [pvm] "v"(pvomax), [hso] "v"(hso),
          [hrb] "v"(hrb), [hwb] "v"(hwb),
          [mg] "v"(mg), [pk] "v"(pk), [qk] "v"(qk)
        : "memory", "scc", "s30", "s34", "s35",
          "v2","v3","v4","v5","v6","v7","v8","v9","v10","v11",
          "v12","v13","v14","v15","v16","v17","v18","v19","v20","v21",
          "v22","v23","v24","v25","v26","v27","v28","v29","v30","v31",
          "v32","v33","v34","v35","v36","v37","v38","v39","v40","v41",
          "v42","v43","v44","v45","v46","v47","v48","v49","v50","v60",
          "v100","v101","v102","v103","v104","v105","v106","v107","v108","v109",
          "v110","v111","v112","v113","v114","v115","v116","v117","v118","v119",
          "v120","v121","v122","v123","v124","v125","v126","v127","v128","v129",
          "v130","v131","v132","v133","v134","v135","v136","v137","v138","v139",
          "v140","v141","v142","v143","v144","v145","v146","v147","v148","v149",
          "v150","v151","v152","v153","v154","v155","v156","v157","v158","v159",
          "v160","v161","v162","v163","v164","v165","v166","v167","v168","v169",
          "v170","v171","v172","v173","v174","v175","v176","v177","v178","v179",
          "v180","v181","v182","v183","v184","v185","v186","v187","v188","v189",
          "v190","v191","v192","v193","v194","v195","v196","v197","v198","v199",
          "v200","v201","v202","v203","v204","v205","v206","v207","v208");

    __syncthreads();
    if (do_head && tid < 64) {
        const int lane = tid;
        float p = hbuf[0][(lane / 25) * 36 + (lane % 25)] * head_w[lane];
        if (lane < 36) {
            const int k2 = 64 + lane;
            p += hbuf[0][(k2 / 25) * 36 + (k2 % 25)] * head_w[k2];
        }
        #pragma unroll
        for (int off = 32; off; off >>= 1) p += __shfl_down(p, off);
        if (lane == 0) out[b] = p + head_b[0];
    }
}

// ====================== x-projection GEMM (MFMA, persistent) =================
__global__ void __launch_bounds__(512, 1)
gemm_pre(const float* __restrict__ hs, const float* __restrict__ Wih,
         const float* __restrict__ bih, const float* __restrict__ bhh,
         float* __restrict__ pre)
{
    extern __shared__ short Ws[];

    const int tid = threadIdx.x;
    const int l   = tid & 63, w = tid >> 6;
    const int lr  = l & 15, lg = l >> 4;
    const int gbase = blockIdx.y * 200;

    {
        int* wz = (int*)Ws;
        for (int i = tid; i < 26624; i += 512) wz[i] = 0;
    }
    __syncthreads();

    for (int L = tid; L < 20000; L += 512) {
        const int g = L / 100, k = L % 100;
        const float v = Wih[(size_t)(gbase + g) * HH + k];
        const unsigned hh = bf16rne(v);
        const float rem = v - __uint_as_float(hh << 16);
        const unsigned lo = bf16rne(rem);
        const int kp = (((k >> 3) ^ (g & 15)) << 3) | (k & 7);
        Ws[(size_t)g * 128 + kp]          = (short)hh;
        Ws[(size_t)(208 + g) * 128 + kp]  = (short)lo;
    }
    __syncthreads();

    for (int c = 0; c < 8; ++c) {
        const int row0   = blockIdx.x * 1024 + c * 128;
        const int t      = row0 >> 9;
        const int b_base = row0 & 511;

        bf16x8 Ahi[4], Alo[4];
        {
            const float* hrow = hs + ((size_t)(b_base + 16 * w + lr) * TT + t) * HH;
            #pragma unroll
            for (int kt = 0; kt < 4; ++kt) {
                const int k0 = 32 * kt + 8 * lg;
                float4 v0 = {0.f,0.f,0.f,0.f}, v1 = {0.f,0.f,0.f,0.f};
                if (k0     <= 96) v0 = *(const float4*)(hrow + k0);
                if (k0 + 4 <= 96) v1 = *(const float4*)(hrow + k0 + 4);
                const float e[8] = {v0.x,v0.y,v0.z,v0.w,v1.x,v1.y,v1.z,v1.w};
                short sh[8], sl[8];
                #pragma unroll
                for (int i = 0; i < 8; ++i) {
                    const unsigned hh = bf16rne(e[i]);
                    const float rem = e[i] - __uint_as_float(hh << 16);
                    sh[i] = (short)hh;
                    sl[i] = (short)bf16rne(rem);
                }
                Ahi[kt] = (bf16x8){sh[0],sh[1],sh[2],sh[3],sh[4],sh[5],sh[6],sh[7]};
                Alo[kt] = (bf16x8){sl[0],sl[1],sl[2],sl[3],sl[4],sl[5],sl[6],sl[7]};
            }
        }

        #pragma unroll
        for (int n = 0; n < 13; ++n) {
            const int gp = 16 * n + lr;
            bf16x8 Bhi[4], Blo[4];
            #pragma unroll
            for (int kt = 0; kt < 4; ++kt) {
                const int slot = (4 * kt + lg) ^ (gp & 15);
                Bhi[kt] = *(const bf16x8*)&Ws[(size_t)gp * 128 + slot * 8];
                Blo[kt] = *(const bf16x8*)&Ws[(size_t)(208 + gp) * 128 + slot * 8];
            }
            f32x4 acc = {0.f, 0.f, 0.f, 0.f};
            #pragma unroll
            for (int kt = 0; kt < 4; ++kt) {
                acc = __builtin_amdgcn_mfma_f32_16x16x32_bf16(Ahi[kt], Bhi[kt], acc, 0, 0, 0);
                acc = __builtin_amdgcn_mfma_f32_16x16x32_bf16(Alo[kt], Bhi[kt], acc, 0, 0, 0);
                acc = __builtin_amdgcn_mfma_f32_16x16x32_bf16(Ahi[kt], Blo[kt], acc, 0, 0, 0);
            }
            if (gp < 200) {
                const int gcol = gbase + gp;
                const float bsum = bih[gcol] + bhh[gcol];
                #pragma unroll
                for (int r = 0; r < 4; ++r) {
                    const size_t row = (size_t)row0 + 16 * w + 4 * lg + r;
                    pre[row * GG + gcol] = acc[r] + bsum;
                }
            }
        }
    }
}

// =============================================================================
extern "C" void kernel_launch(void* const* d_in, const int* in_sizes, int n_in,
                              void* d_out, int out_size, void* d_ws, size_t ws_size,
                              hipStream_t stream) {
    const float* x         = (const float*)d_in[0];
    const float* W_ih0     = (const float*)d_in[1];
    const float* W_ih_rest = (const float*)d_in[2];
    const float* W_hh      = (const float*)d_in[3];
    const float* b_ih      = (const float*)d_in[4];
    const float* b_hh      = (const float*)d_in[5];
    const float* head_w    = (const float*)d_in[6];
    const float* head_b    = (const float*)d_in[7];
    float* out = (float*)d_out;

    const size_t HS_BYTES = (size_t)BB * TT * HH * 4;
    float* hs  = (float*)d_ws;
    float* pre = (float*)((char*)d_ws + HS_BYTES);

    const int gemm_lds = 2 * 208 * 128 * 2;
    hipFuncSetAttribute((const void*)gemm_pre,
                        hipFuncAttributeMaxDynamicSharedMemorySize, gemm_lds);
    dim3 ggrid(128, 2);

    lstm_recur<0><<<512, 448, 0, stream>>>(
        x, nullptr, W_hh, W_ih0, b_ih, b_hh, head_w, head_b, hs, out);

    gemm_pre<<<ggrid, 512, gemm_lds, stream>>>(hs, W_ih_rest, b_ih + GG, b_hh + GG, pre);
    lstm_recur_asm<<<512, 448, 0, stream>>>(
        pre, W_hh + 40000, head_w, head_b, hs, out, 0);

    gemm_pre<<<ggrid, 512, gemm_lds, stream>>>(hs, W_ih_rest + 40000, b_ih + 2*GG, b_hh + 2*GG, pre);
    lstm_recur_asm<<<512, 448, 0, stream>>>(
        pre, W_hh + 80000, head_w, head_b, hs, out, 1);
}